// Round 1
// baseline (229.292 us; speedup 1.0000x reference)
//
#include <hip/hip_runtime.h>

#define B_N 32
#define C_K 512
#define T_N 1024
#define D_M 512

constexpr int BM = 128;
constexpr int BN = 128;
constexpr int BK = 32;
constexpr int SA = 40; // LDS row stride in bf16 elems: 32 + 8 pad -> 80B rows, 16B-aligned

typedef __attribute__((ext_vector_type(4))) float floatx4;
typedef __attribute__((ext_vector_type(8))) short shortx8;

__device__ __forceinline__ short f2bf(float f) {
  union { float f; unsigned u; } v; v.f = f;
  unsigned r = v.u + 0x7fffu + ((v.u >> 16) & 1u); // round-to-nearest-even
  return (short)(r >> 16);
}

// out[b,d,t] = sum_c x[b,c,t] * weights[sub[b],c,d] + bias[sub[b],d]
// GEMM per b: A = W (K x M, m-contiguous), B = X (K x N, n-contiguous), C = (M x N)
__global__ __launch_bounds__(256, 2)
void subject_gemm(const float* __restrict__ x, const int* __restrict__ subjects,
                  const float* __restrict__ weights, const float* __restrict__ bias,
                  float* __restrict__ out)
{
  __shared__ short lds_a[BM * SA]; // [m][k], k-contiguous, padded
  __shared__ short lds_b[BN * SA]; // [n][k]

  const int bid = blockIdx.x;
  const int b   = bid >> 5;        // batch
  const int tm  = (bid >> 3) & 3;  // d-tile (D/128 = 4)
  const int tn  = bid & 7;         // t-tile (T/128 = 8)
  const int m0  = tm * BM;
  const int n0  = tn * BN;
  const int nb  = subjects[b];

  const float* __restrict__ W = weights + (size_t)nb * C_K * D_M; // [k][m]
  const float* __restrict__ X = x + (size_t)b * C_K * T_N;        // [k][n]

  const int tid  = threadIdx.x;
  const int mp   = tid & 63;   // m-pair index (2 consecutive m per thread)
  const int oct  = tid >> 6;   // k-octet 0..3
  const int lane = tid & 63;
  const int wave = tid >> 6;
  const int wm   = (wave & 1) * 64;
  const int wn   = (wave >> 1) * 64;
  const int l15  = lane & 15;
  const int q    = lane >> 4;

  floatx4 acc[4][4] = {};

  const float* srcA = W + (size_t)(8 * oct) * D_M + (m0 + 2 * mp);
  const float* srcB = X + (size_t)(8 * oct) * T_N + (n0 + 2 * mp);
  short* dstA0 = &lds_a[(2 * mp + 0) * SA + 8 * oct];
  short* dstA1 = &lds_a[(2 * mp + 1) * SA + 8 * oct];
  short* dstB0 = &lds_b[(2 * mp + 0) * SA + 8 * oct];
  short* dstB1 = &lds_b[(2 * mp + 1) * SA + 8 * oct];

  for (int ks = 0; ks < C_K; ks += BK) {
    // ---- stage: global fp32 -> regs -> bf16 -> LDS (transposing to [mn][k]) ----
    shortx8 a0, a1, b0, b1;
    #pragma unroll
    for (int jj = 0; jj < 8; ++jj) {
      float2 v = *(const float2*)(srcA + (size_t)jj * D_M);
      a0[jj] = f2bf(v.x);
      a1[jj] = f2bf(v.y);
    }
    #pragma unroll
    for (int jj = 0; jj < 8; ++jj) {
      float2 v = *(const float2*)(srcB + (size_t)jj * T_N);
      b0[jj] = f2bf(v.x);
      b1[jj] = f2bf(v.y);
    }
    *(shortx8*)dstA0 = a0;  // ds_write_b128, 8 k's for one m-row
    *(shortx8*)dstA1 = a1;
    *(shortx8*)dstB0 = b0;
    *(shortx8*)dstB1 = b1;
    __syncthreads();

    // ---- fragments + MFMA ----
    shortx8 af[4], bg[4];
    #pragma unroll
    for (int i = 0; i < 4; ++i) {
      af[i] = *(const shortx8*)&lds_a[(wm + 16 * i + l15) * SA + 8 * q];
      bg[i] = *(const shortx8*)&lds_b[(wn + 16 * i + l15) * SA + 8 * q];
    }
    #pragma unroll
    for (int i = 0; i < 4; ++i)
      #pragma unroll
      for (int j = 0; j < 4; ++j)
        acc[i][j] = __builtin_amdgcn_mfma_f32_16x16x32_bf16(af[i], bg[j], acc[i][j], 0, 0, 0);
    __syncthreads();

    srcA += (size_t)BK * D_M;
    srcB += (size_t)BK * T_N;
  }

  // ---- epilogue: C/D layout col = lane&15 (t), row = 4*(lane>>4) + reg (d) ----
  float* __restrict__ O = out + (size_t)b * D_M * T_N;
  const float* __restrict__ bb = bias + (size_t)nb * D_M;
  #pragma unroll
  for (int i = 0; i < 4; ++i) {
    #pragma unroll
    for (int r = 0; r < 4; ++r) {
      const int d = m0 + wm + 16 * i + 4 * q + r;
      const float bv = bb[d];
      #pragma unroll
      for (int j = 0; j < 4; ++j) {
        const int t = n0 + wn + 16 * j + l15;
        O[(size_t)d * T_N + t] = acc[i][j][r] + bv;
      }
    }
  }
}

extern "C" void kernel_launch(void* const* d_in, const int* in_sizes, int n_in,
                              void* d_out, int out_size, void* d_ws, size_t ws_size,
                              hipStream_t stream) {
  const float* x        = (const float*)d_in[0];
  const int*   subjects = (const int*)d_in[1];
  const float* weights  = (const float*)d_in[2];
  const float* bias     = (const float*)d_in[3];
  float* out = (float*)d_out;
  (void)in_sizes; (void)n_in; (void)out_size; (void)d_ws; (void)ws_size;

  dim3 grid(B_N * 4 * 8); // 32 batches x 4 d-tiles x 8 t-tiles = 1024 blocks
  dim3 block(256);
  hipLaunchKernelGGL(subject_gemm, grid, block, 0, stream, x, subjects, weights, bias, out);
}

// Round 2
// 194.258 us; speedup vs baseline: 1.1803x; 1.1803x over previous
//
#include <hip/hip_runtime.h>

#define B_N 32
#define C_K 512
#define T_N 1024
#define D_M 512

constexpr int BM = 128;
constexpr int BN = 128;
constexpr int BK = 32;
constexpr int SA = 36; // LDS row stride in shorts: 32 + 4 pad = 72B rows (8B-aligned)
constexpr int KSTEPS = C_K / BK; // 16

typedef __attribute__((ext_vector_type(4))) float floatx4;
typedef __attribute__((ext_vector_type(8))) short shortx8;
typedef __attribute__((ext_vector_type(4))) short shortx4;

__device__ __forceinline__ short f2bf(float f) {
  union { float f; unsigned u; } v; v.f = f;
  unsigned r = v.u + 0x7fffu + ((v.u >> 16) & 1u); // round-to-nearest-even
  return (short)(r >> 16);
}

// out[b,d,t] = sum_c x[b,c,t] * weights[sub[b],c,d] + bias[sub[b],d]
// Per-b GEMM: A = W[nb] (K x M, m-contig), B = X[b] (K x N, n-contig), C = (M x N)
__global__ __launch_bounds__(256, 3)
void subject_gemm(const float* __restrict__ x, const int* __restrict__ subjects,
                  const float* __restrict__ weights, const float* __restrict__ bias,
                  float* __restrict__ out)
{
  __shared__ short lds_a[2][BM * SA]; // [m][k] bf16, k-contiguous rows
  __shared__ short lds_b[2][BN * SA]; // [n][k]

  const int bid = blockIdx.x;
  const int b   = bid >> 5;        // batch
  const int tm  = (bid >> 3) & 3;  // d-tile (D/128 = 4)
  const int tn  = bid & 7;         // t-tile (T/128 = 8)
  const int m0  = tm * BM;
  const int n0  = tn * BN;
  const int nb  = subjects[b];

  const float* __restrict__ W = weights + (size_t)nb * C_K * D_M; // [k][m]
  const float* __restrict__ X = x + (size_t)b * C_K * T_N;        // [k][n]

  const int tid  = threadIdx.x;
  const int mp   = tid & 63;   // m-pair index (2 consecutive m/n per thread)
  const int oct  = tid >> 6;   // k-octet 0..3 (k = 8*oct + jj)
  const int lane = tid & 63;
  const int wave = tid >> 6;
  const int wm   = (wave & 1) * 64;
  const int wn   = (wave >> 1) * 64;
  const int l15  = lane & 15;
  const int q    = lane >> 4;

  floatx4 acc[4][4] = {};

  const float* srcA = W + (size_t)(8 * oct) * D_M + (m0 + 2 * mp);
  const float* srcB = X + (size_t)(8 * oct) * T_N + (n0 + 2 * mp);

  // LDS write targets: rows 2mp and 2mp+1, k-offset 8*oct shorts
  short* wA0 = &lds_a[0][(2 * mp + 0) * SA + 8 * oct];
  short* wA1 = &lds_a[0][(2 * mp + 1) * SA + 8 * oct];
  short* wB0 = &lds_b[0][(2 * mp + 0) * SA + 8 * oct];
  short* wB1 = &lds_b[0][(2 * mp + 1) * SA + 8 * oct];
  const int bufoff_a = BM * SA; // shorts between buffer 0 and 1
  const int bufoff_b = BN * SA;

  float2 va[8], vb[8];

  // ---- prologue: load tile 0, stage into buf 0 ----
  #pragma unroll
  for (int jj = 0; jj < 8; ++jj) va[jj] = *(const float2*)(srcA + (size_t)jj * D_M);
  #pragma unroll
  for (int jj = 0; jj < 8; ++jj) vb[jj] = *(const float2*)(srcB + (size_t)jj * T_N);
  srcA += (size_t)BK * D_M;
  srcB += (size_t)BK * T_N;

  {
    shortx4 a0l, a0h, a1l, a1h, b0l, b0h, b1l, b1h;
    #pragma unroll
    for (int jj = 0; jj < 4; ++jj) {
      a0l[jj] = f2bf(va[jj].x);     a1l[jj] = f2bf(va[jj].y);
      a0h[jj] = f2bf(va[4 + jj].x); a1h[jj] = f2bf(va[4 + jj].y);
      b0l[jj] = f2bf(vb[jj].x);     b1l[jj] = f2bf(vb[jj].y);
      b0h[jj] = f2bf(vb[4 + jj].x); b1h[jj] = f2bf(vb[4 + jj].y);
    }
    *(shortx4*)(wA0) = a0l; *(shortx4*)(wA0 + 4) = a0h;
    *(shortx4*)(wA1) = a1l; *(shortx4*)(wA1 + 4) = a1h;
    *(shortx4*)(wB0) = b0l; *(shortx4*)(wB0 + 4) = b0h;
    *(shortx4*)(wB1) = b1l; *(shortx4*)(wB1 + 4) = b1h;
  }

  // ---- pipelined main loop: 1 barrier/kstep, global latency hidden by MFMA ----
  for (int ks = 0; ks < KSTEPS; ++ks) {
    const int p = ks & 1;

    if (ks < KSTEPS - 1) {
      // issue global loads for tile ks+1 (no wait until after MFMA)
      #pragma unroll
      for (int jj = 0; jj < 8; ++jj) va[jj] = *(const float2*)(srcA + (size_t)jj * D_M);
      #pragma unroll
      for (int jj = 0; jj < 8; ++jj) vb[jj] = *(const float2*)(srcB + (size_t)jj * T_N);
      srcA += (size_t)BK * D_M;
      srcB += (size_t)BK * T_N;
    }

    __syncthreads(); // tile ks's writes (prev iter / prologue) now visible

    // fragments from buf p (conflict-free b64 reads) + MFMA
    shortx8 af[4], bg[4];
    #pragma unroll
    for (int i = 0; i < 4; ++i) {
      const short* pa = &lds_a[p][(wm + 16 * i + l15) * SA + 8 * q];
      const short* pb = &lds_b[p][(wn + 16 * i + l15) * SA + 8 * q];
      shortx4 alo = *(const shortx4*)pa;
      shortx4 ahi = *(const shortx4*)(pa + 4);
      shortx4 blo = *(const shortx4*)pb;
      shortx4 bhi = *(const shortx4*)(pb + 4);
      af[i] = __builtin_shufflevector(alo, ahi, 0, 1, 2, 3, 4, 5, 6, 7);
      bg[i] = __builtin_shufflevector(blo, bhi, 0, 1, 2, 3, 4, 5, 6, 7);
    }
    #pragma unroll
    for (int i = 0; i < 4; ++i)
      #pragma unroll
      for (int j = 0; j < 4; ++j)
        acc[i][j] = __builtin_amdgcn_mfma_f32_16x16x32_bf16(af[i], bg[j], acc[i][j], 0, 0, 0);

    if (ks < KSTEPS - 1) {
      // cvt (vmcnt wait lands here, after MFMA) and stage tile ks+1 into buf p^1
      const int off_a = (p ^ 1) ? bufoff_a : 0;
      const int off_b = (p ^ 1) ? bufoff_b : 0;
      shortx4 a0l, a0h, a1l, a1h, b0l, b0h, b1l, b1h;
      #pragma unroll
      for (int jj = 0; jj < 4; ++jj) {
        a0l[jj] = f2bf(va[jj].x);     a1l[jj] = f2bf(va[jj].y);
        a0h[jj] = f2bf(va[4 + jj].x); a1h[jj] = f2bf(va[4 + jj].y);
        b0l[jj] = f2bf(vb[jj].x);     b1l[jj] = f2bf(vb[jj].y);
        b0h[jj] = f2bf(vb[4 + jj].x); b1h[jj] = f2bf(vb[4 + jj].y);
      }
      *(shortx4*)(wA0 + off_a) = a0l; *(shortx4*)(wA0 + off_a + 4) = a0h;
      *(shortx4*)(wA1 + off_a) = a1l; *(shortx4*)(wA1 + off_a + 4) = a1h;
      *(shortx4*)(wB0 + off_b) = b0l; *(shortx4*)(wB0 + off_b + 4) = b0h;
      *(shortx4*)(wB1 + off_b) = b1l; *(shortx4*)(wB1 + off_b + 4) = b1h;
    }
  }

  // ---- epilogue: C/D layout col = lane&15 (t), row = 4*(lane>>4) + reg (d) ----
  float* __restrict__ O = out + (size_t)b * D_M * T_N;
  const float* __restrict__ bb = bias + (size_t)nb * D_M;
  #pragma unroll
  for (int i = 0; i < 4; ++i) {
    #pragma unroll
    for (int r = 0; r < 4; ++r) {
      const int d = m0 + wm + 16 * i + 4 * q + r;
      const float bv = bb[d];
      #pragma unroll
      for (int j = 0; j < 4; ++j) {
        const int t = n0 + wn + 16 * j + l15;
        O[(size_t)d * T_N + t] = acc[i][j][r] + bv;
      }
    }
  }
}

extern "C" void kernel_launch(void* const* d_in, const int* in_sizes, int n_in,
                              void* d_out, int out_size, void* d_ws, size_t ws_size,
                              hipStream_t stream) {
  const float* x        = (const float*)d_in[0];
  const int*   subjects = (const int*)d_in[1];
  const float* weights  = (const float*)d_in[2];
  const float* bias     = (const float*)d_in[3];
  float* out = (float*)d_out;
  (void)in_sizes; (void)n_in; (void)out_size; (void)d_ws; (void)ws_size;

  dim3 grid(B_N * 4 * 8); // 32 batches x 4 d-tiles x 8 t-tiles = 1024 blocks
  dim3 block(256);
  hipLaunchKernelGGL(subject_gemm, grid, block, 0, stream, x, subjects, weights, bias, out);
}

// Round 3
// 180.300 us; speedup vs baseline: 1.2717x; 1.0774x over previous
//
#include <hip/hip_runtime.h>
#include <hip/hip_bf16.h>

#define B_N 32
#define C_K 512
#define T_N 1024
#define D_M 512

constexpr int BM = 128, BN = 128, BK = 32;
constexpr int SA = 36;            // shorts per LDS row (72B): bank-balanced, 8B-aligned
constexpr int KSTEPS = C_K / BK;  // 16

typedef __attribute__((ext_vector_type(4))) float  floatx4;
typedef __attribute__((ext_vector_type(4))) short  shortx4;
typedef __attribute__((ext_vector_type(8))) short  shortx8;
typedef __attribute__((ext_vector_type(2))) unsigned int uintx2;

__device__ __forceinline__ unsigned pk2(float a, float b) {
  __hip_bfloat162 h = __float22bfloat162_rn(make_float2(a, b));
  union { __hip_bfloat162 v; unsigned u; } c; c.v = h; return c.u;
}

// out[b,d,t] = sum_c x[b,c,t] * W[sub[b],c,d] + bias[sub[b],d]
// Per-b GEMM: A = W[nb] (K x M, m-contig), B = X[b] (K x N, n-contig)
__global__ __launch_bounds__(256, 3)
void subject_gemm(const float* __restrict__ x, const int* __restrict__ subjects,
                  const float* __restrict__ weights, const float* __restrict__ bias,
                  float* __restrict__ out)
{
  __shared__ short lds_a[2][BM * SA]; // [m][k] bf16
  __shared__ short lds_b[2][BN * SA]; // [n][k]

  // XCD-aware swizzle: xcd = bid%8 (dispatch heuristic); all 32 tiles of a batch
  // land on one XCD -> per-XCD/kstep working set ~768KB << 4MiB L2.
  const int bid  = blockIdx.x;
  const int xcd  = bid & 7;
  const int s    = bid >> 3;           // 0..127
  const int b    = xcd * 4 + (s & 3);  // 4 batches per XCD
  const int tile = s >> 2;             // 0..31
  const int tm = tile >> 3, tn = tile & 7;
  const int m0 = tm * BM, n0 = tn * BN;
  const int nb = subjects[b];

  const float* __restrict__ Wp = weights + (size_t)nb * C_K * D_M; // [k][m]
  const float* __restrict__ Xp = x + (size_t)b * C_K * T_N;        // [k][n]

  const int tid  = threadIdx.x;
  const int lane = tid & 63;
  const int wave = tid >> 6;

  // ---- staging role: waves 0-1 stage A, waves 2-3 stage B ----
  const bool isA = (wave < 2);
  const int  mg  = (wave & 1) * 16 + (lane & 15); // 4 m/n-columns starting at 4*mg
  const int  oct = lane >> 4;                     // k = 8*oct + jj
  const float* gsrc = isA ? (Wp + (size_t)(8 * oct) * D_M + (m0 + 4 * mg))
                          : (Xp + (size_t)(8 * oct) * T_N + (n0 + 4 * mg));
  const int gs = isA ? D_M : T_N;
  short* const wbase = (isA ? &lds_a[0][0] : &lds_b[0][0]) + (4 * mg) * SA + 8 * oct;
  constexpr int BUFO = BM * SA;

  // ---- compute role: wave tile 64x64 ----
  const int wm = (wave & 1) * 64, wn = (wave >> 1) * 64;
  const int l15 = lane & 15, q = lane >> 4;

  floatx4 acc[4][4] = {};
  floatx4 v[8];

  // ---- prologue: load+stage tile 0 into buf 0 ----
  #pragma unroll
  for (int jj = 0; jj < 8; ++jj)
    v[jj] = *(const floatx4*)(gsrc + (size_t)jj * gs);
  gsrc += (size_t)BK * gs;
  #pragma unroll
  for (int r = 0; r < 4; ++r) {
    uintx2 lo = { pk2(v[0][r], v[1][r]), pk2(v[2][r], v[3][r]) };
    uintx2 hi = { pk2(v[4][r], v[5][r]), pk2(v[6][r], v[7][r]) };
    *(uintx2*)(wbase + r * SA)     = lo;
    *(uintx2*)(wbase + r * SA + 4) = hi;
  }

  for (int ks = 0; ks < KSTEPS; ++ks) {
    const int p = ks & 1;
    __syncthreads(); // buf p ready; also drains any outstanding vmem (cheap here)

    // issue next tile's loads AFTER the barrier so they stay in flight
    // across frag reads + MFMA (vmcnt wait lands at the cvt block below)
    if (ks + 1 < KSTEPS) {
      #pragma unroll
      for (int jj = 0; jj < 8; ++jj)
        v[jj] = *(const floatx4*)(gsrc + (size_t)jj * gs);
      gsrc += (size_t)BK * gs;
    }

    // fragments from buf p (b64 pairs, bank-balanced)
    const short* pa = &lds_a[p][0] + (wm + l15) * SA + 8 * q;
    const short* pb = &lds_b[p][0] + (wn + l15) * SA + 8 * q;
    shortx8 af[4], bg[4];
    #pragma unroll
    for (int i = 0; i < 4; ++i) {
      shortx4 alo = *(const shortx4*)(pa + 16 * i * SA);
      shortx4 ahi = *(const shortx4*)(pa + 16 * i * SA + 4);
      shortx4 blo = *(const shortx4*)(pb + 16 * i * SA);
      shortx4 bhi = *(const shortx4*)(pb + 16 * i * SA + 4);
      af[i] = __builtin_shufflevector(alo, ahi, 0, 1, 2, 3, 4, 5, 6, 7);
      bg[i] = __builtin_shufflevector(blo, bhi, 0, 1, 2, 3, 4, 5, 6, 7);
    }
    #pragma unroll
    for (int i = 0; i < 4; ++i)
      #pragma unroll
      for (int j = 0; j < 4; ++j)
        acc[i][j] = __builtin_amdgcn_mfma_f32_16x16x32_bf16(af[i], bg[j], acc[i][j], 0, 0, 0);

    // cvt (vmcnt wait lands HERE, after MFMA) + stage into buf p^1
    if (ks + 1 < KSTEPS) {
      short* wdst = wbase + (p ^ 1) * BUFO;
      #pragma unroll
      for (int r = 0; r < 4; ++r) {
        uintx2 lo = { pk2(v[0][r], v[1][r]), pk2(v[2][r], v[3][r]) };
        uintx2 hi = { pk2(v[4][r], v[5][r]), pk2(v[6][r], v[7][r]) };
        *(uintx2*)(wdst + r * SA)     = lo;
        *(uintx2*)(wdst + r * SA + 4) = hi;
      }
    }
  }

  // ---- epilogue: C/D layout col = lane&15 (t), row = 4*(lane>>4) + reg (d) ----
  float* __restrict__ O = out + (size_t)b * D_M * T_N;
  const float* __restrict__ bb = bias + (size_t)nb * D_M;
  #pragma unroll
  for (int i = 0; i < 4; ++i) {
    #pragma unroll
    for (int r = 0; r < 4; ++r) {
      const int d = m0 + wm + 16 * i + 4 * q + r;
      const float bv = bb[d];
      #pragma unroll
      for (int j = 0; j < 4; ++j) {
        const int t = n0 + wn + 16 * j + l15;
        O[(size_t)d * T_N + t] = acc[i][j][r] + bv;
      }
    }
  }
}

extern "C" void kernel_launch(void* const* d_in, const int* in_sizes, int n_in,
                              void* d_out, int out_size, void* d_ws, size_t ws_size,
                              hipStream_t stream) {
  const float* x        = (const float*)d_in[0];
  const int*   subjects = (const int*)d_in[1];
  const float* weights  = (const float*)d_in[2];
  const float* bias     = (const float*)d_in[3];
  float* out = (float*)d_out;
  (void)in_sizes; (void)n_in; (void)out_size; (void)d_ws; (void)ws_size;

  dim3 grid(B_N * 4 * 8); // 1024 blocks: 32 b x 4 tm x 8 tn
  dim3 block(256);
  hipLaunchKernelGGL(subject_gemm, grid, block, 0, stream, x, subjects, weights, bias, out);
}